// Round 6
// baseline (70.491 us; speedup 1.0000x reference)
//
#include <hip/hip_runtime.h>

typedef __bf16 bf16;
typedef __bf16 bf16x4 __attribute__((ext_vector_type(4)));
typedef __bf16 bf16x8 __attribute__((ext_vector_type(8)));
typedef float f32x4 __attribute__((ext_vector_type(4)));

#define SEQ 1024
#define EMB 1024
#define NH 16
#define HD 64
#define M2 2047   // 2*MAX_POS - 1

// ---------------------------------------------------------------------------
// Kernel 1 (R2 version, unchanged): P[2048][1024] (bf16) = gather(posEmb) @ W
// ---------------------------------------------------------------------------
__global__ __launch_bounds__(256) void gemm1_kernel(const float* __restrict__ posEmb,
                                                    const float* __restrict__ W,
                                                    bf16* __restrict__ P) {
  __shared__ bf16 As[64][72];
  __shared__ bf16 Bs[64][72];
  const int tid  = threadIdx.x;
  const int lane = tid & 63;
  const int wave = tid >> 6;
  const int wr = wave >> 1, wc = wave & 1;
  const int m0 = blockIdx.y * 64;
  const int n0 = blockIdx.x * 64;

  f32x4 acc[2][2] = {};

  for (int k0 = 0; k0 < EMB; k0 += 64) {
    {
      const int row = tid >> 2;
      const int c0  = (tid & 3) * 16;
      int g = m0 + row;
      if (g > M2 - 1) g = M2 - 1;
      const float4* src = reinterpret_cast<const float4*>(posEmb + (size_t)g * EMB + k0 + c0);
      #pragma unroll
      for (int i = 0; i < 4; ++i) {
        float4 v = src[i];
        bf16x4 bb = { (bf16)v.x, (bf16)v.y, (bf16)v.z, (bf16)v.w };
        *reinterpret_cast<bf16x4*>(&As[row][c0 + 4 * i]) = bb;
      }
    }
    {
      const int n  = tid & 63;
      const int kg = tid >> 6;
      #pragma unroll
      for (int u = 0; u < 4; ++u) {
        bf16x4 bb;
        #pragma unroll
        for (int e = 0; e < 4; ++e) {
          int k = kg * 16 + u * 4 + e;
          bb[e] = (bf16)W[(size_t)(k0 + k) * EMB + n0 + n];
        }
        *reinterpret_cast<bf16x4*>(&Bs[n][kg * 16 + u * 4]) = bb;
      }
    }
    __syncthreads();
    #pragma unroll
    for (int ks = 0; ks < 2; ++ks) {
      bf16x8 a[2], b[2];
      #pragma unroll
      for (int x = 0; x < 2; ++x) {
        a[x] = *reinterpret_cast<const bf16x8*>(&As[wr * 32 + x * 16 + (lane & 15)][ks * 32 + 8 * (lane >> 4)]);
        b[x] = *reinterpret_cast<const bf16x8*>(&Bs[wc * 32 + x * 16 + (lane & 15)][ks * 32 + 8 * (lane >> 4)]);
      }
      #pragma unroll
      for (int x = 0; x < 2; ++x)
        #pragma unroll
        for (int y = 0; y < 2; ++y)
          acc[x][y] = __builtin_amdgcn_mfma_f32_16x16x32_bf16(a[x], b[y], acc[x][y], 0, 0, 0);
    }
    __syncthreads();
  }

  #pragma unroll
  for (int x = 0; x < 2; ++x)
    #pragma unroll
    for (int y = 0; y < 2; ++y)
      #pragma unroll
      for (int r = 0; r < 4; ++r) {
        int row = m0 + wr * 32 + x * 16 + (lane >> 4) * 4 + r;
        int col = n0 + wc * 32 + y * 16 + (lane & 15);
        P[(size_t)row * EMB + col] = (bf16)acc[x][y][r];
      }
}

// ---------------------------------------------------------------------------
// Kernel 2 (REWRITTEN, band3): 16-row i-slab per block, LDS accumulation,
// fully-linear 64 KB flush.
//   grid = (64 i-tiles, 32 hb), block = 256 (4 waves; wave w owns m-frag w).
//   Per tile: 64 m-rows x 64 k of P (swizzled global_load_lds dbuf) x Q(16x64).
//   Shift-scatter goes to LDS slab[16][1024]; final flush streams 1KB/wave-instr
//   contiguous float4 stores (fill-kernel pattern) for DRAM page locality.
// ---------------------------------------------------------------------------
__global__ __launch_bounds__(256) void band3_kernel(const float* __restrict__ q,
                                                    const bf16* __restrict__ P,
                                                    float* __restrict__ out) {
  __shared__ float slab[16 * 1024];     // 64 KB accumulation slab
  __shared__ bf16  Pbuf[2][64 * 64];    // 16 KB double-buffered P tile
  const int tid  = threadIdx.x;
  const int lane = tid & 63;
  const int wave = tid >> 6;

  const int i0 = blockIdx.x * 16;       // 0..1008
  const int hb = blockIdx.y;            // h*2 + b
  const int h  = hb >> 1;
  const int b  = hb & 1;

  // ---- Q fragments (16 rows x 64 k), direct global f32 -> bf16x8 regs.
  // a[ks]: row = i0 + (lane&15), k = ks*32 + 8*(lane>>4). All waves identical.
  bf16x8 a[2];
  {
    const float* src0 = q + ((size_t)(h * (2 * SEQ) + b * SEQ + i0 + (lane & 15))) * HD;
    #pragma unroll
    for (int ks = 0; ks < 2; ++ks) {
      const float* s = src0 + ks * 32 + 8 * (lane >> 4);
      float4 v0 = *reinterpret_cast<const float4*>(s);
      float4 v1 = *reinterpret_cast<const float4*>(s + 4);
      bf16x8 f = { (bf16)v0.x, (bf16)v0.y, (bf16)v0.z, (bf16)v0.w,
                   (bf16)v1.x, (bf16)v1.y, (bf16)v1.z, (bf16)v1.w };
      a[ks] = f;
    }
  }

  const int m_base = (SEQ - 1) - (i0 + 15);   // 0..1008; 17 tiles cover j fully

  // stage tile t into Pbuf[bi]: 64 m-rows x 64 k, swizzled source, linear dest.
  auto STAGE = [&](int bi, int t) {
    const char* Pb = reinterpret_cast<const char*>(P);
    #pragma unroll
    for (int i = 0; i < 2; ++i) {
      int s   = wave * 128 + i * 64 + lane;   // 16B chunk slot
      int row = s >> 3;
      int cs  = s & 7;
      int cd  = cs ^ (row & 7);
      int gm  = m_base + t * 64 + row;
      if (gm > M2) gm = M2;                   // clamped rows only feed masked j
      const void* g = Pb + ((size_t)gm * EMB + h * HD) * 2 + cd * 16;
      char* l = reinterpret_cast<char*>(&Pbuf[bi][0]) + s * 16;
      __builtin_amdgcn_global_load_lds(
          (const __attribute__((address_space(1))) void*)g,
          (__attribute__((address_space(3))) void*)l, 16, 0, 0);
    }
  };

  STAGE(0, 0);
  __syncthreads();

  int cur = 0;
  for (int t = 0; t < 17; ++t) {
    if (t < 16) STAGE(cur ^ 1, t + 1);

    // ---- compute 16x64 score sub-tile from Pbuf[cur]
    const char* buf = reinterpret_cast<const char*>(&Pbuf[cur][0]);
    f32x4 acc = {};
    #pragma unroll
    for (int ks = 0; ks < 2; ++ks) {
      int mrow  = wave * 16 + (lane & 15);
      int chunk = ks * 4 + (lane >> 4);
      int sw    = chunk ^ (mrow & 7);
      bf16x8 pb = *reinterpret_cast<const bf16x8*>(buf + mrow * 128 + sw * 16);
      acc = __builtin_amdgcn_mfma_f32_16x16x32_bf16(a[ks], pb, acc, 0, 0, 0);
    }

    // ---- shift-scatter into LDS slab (each (il,j) written exactly once)
    const int m0 = m_base + t * 64;
    const int mloc = m0 + wave * 16 + (lane & 15);
    #pragma unroll
    for (int r = 0; r < 4; ++r) {
      int il = (lane >> 4) * 4 + r;
      int j  = mloc - (SEQ - 1) + i0 + il;
      if ((unsigned)j < SEQ) slab[il * SEQ + j] = acc[r];
    }

    __syncthreads();
    cur ^= 1;
  }

  // ---- flush: 64 KB perfectly linear (1 KB contiguous per wave-store)
  const size_t outb = ((size_t)hb << 20) + (size_t)i0 * SEQ;
  #pragma unroll
  for (int c = 0; c < 16; ++c) {
    int flat = c * 1024 + tid * 4;
    float4 v = *reinterpret_cast<const float4*>(&slab[flat]);
    *reinterpret_cast<float4*>(&out[outb + flat]) = v;
  }
}

extern "C" void kernel_launch(void* const* d_in, const int* in_sizes, int n_in,
                              void* d_out, int out_size, void* d_ws, size_t ws_size,
                              hipStream_t stream) {
  const float* query  = (const float*)d_in[0];   // [2,16,1024,64]
  const float* posEmb = (const float*)d_in[1];   // [2047,1024]
  const float* W      = (const float*)d_in[2];   // [1024,1024]
  float* out = (float*)d_out;                    // [2,16,1024,1024]
  bf16* P = (bf16*)d_ws;                         // [2048][1024] bf16 = 4 MB

  gemm1_kernel<<<dim3(16, 32), 256, 0, stream>>>(posEmb, W, P);
  band3_kernel<<<dim3(64, 32), 256, 0, stream>>>(query, P, out);
}